// Round 1
// baseline (2662.412 us; speedup 1.0000x reference)
//
#include <hip/hip_runtime.h>
#include <cstdint>

typedef unsigned long long u64;

#define TPB 256

// ---------------------------------------------------------------------------
// gamma^dist table, fp64. pw[h*512 + dist]
__global__ void pow_kernel(double* __restrict__ pw) {
    int h = threadIdx.x;
    if (h < 8) {
        double gamma = 1.0 - ldexp(1.0, -5 - h);   // 1 - 2^-(5+h), exact
        double p = 1.0;
        for (int i = 0; i < 512; ++i) { pw[h * 512 + i] = p; p *= gamma; }
    }
}

// ---------------------------------------------------------------------------
// out[m,d] = BN( sum_c A[m,c]*W[d,c] + bias[d] ), fp64 accumulation.
// A: 16384 x 512 (row-major), W: 512 x 512 (row-major, [d][c]), out fp32.
// Tiles: BM=64, BD=64, BK=32; 256 threads; 4x4 outputs/thread.
__global__ __launch_bounds__(256) void gemm_bn(
    const float* __restrict__ A, const float* __restrict__ W,
    const float* __restrict__ bias,
    const float* __restrict__ bnw, const float* __restrict__ bnb,
    const float* __restrict__ bnm, const float* __restrict__ bnv,
    float* __restrict__ out)
{
    const int K = 512;
    __shared__ float As[64][36];   // pad 36: 144B rows (16B aligned), conflicts <=2-way
    __shared__ float Ws[64][36];

    const int tid = threadIdx.x;
    const int m0 = blockIdx.x * 64;
    const int d0 = blockIdx.y * 64;
    const int lr = tid >> 3;           // 0..31
    const int lc = (tid & 7) << 2;     // 0,4,...,28
    const int tm = tid >> 4;           // 0..15
    const int td = tid & 15;           // 0..15

    double acc[4][4];
    #pragma unroll
    for (int i = 0; i < 4; ++i)
        #pragma unroll
        for (int j = 0; j < 4; ++j) acc[i][j] = 0.0;

    for (int k0 = 0; k0 < K; k0 += 32) {
        float4 a0 = *(const float4*)(A + (size_t)(m0 + lr) * K + k0 + lc);
        float4 a1 = *(const float4*)(A + (size_t)(m0 + lr + 32) * K + k0 + lc);
        float4 w0 = *(const float4*)(W + (size_t)(d0 + lr) * K + k0 + lc);
        float4 w1 = *(const float4*)(W + (size_t)(d0 + lr + 32) * K + k0 + lc);
        __syncthreads();
        *(float4*)&As[lr][lc]      = a0;
        *(float4*)&As[lr + 32][lc] = a1;
        *(float4*)&Ws[lr][lc]      = w0;
        *(float4*)&Ws[lr + 32][lc] = w1;
        __syncthreads();
        #pragma unroll 8
        for (int kk = 0; kk < 32; ++kk) {
            double av[4], wv[4];
            #pragma unroll
            for (int i = 0; i < 4; ++i) av[i] = (double)As[tm + 16 * i][kk];
            #pragma unroll
            for (int j = 0; j < 4; ++j) wv[j] = (double)Ws[td + 16 * j][kk];
            #pragma unroll
            for (int i = 0; i < 4; ++i)
                #pragma unroll
                for (int j = 0; j < 4; ++j)
                    acc[i][j] += av[i] * wv[j];
        }
    }

    #pragma unroll
    for (int j = 0; j < 4; ++j) {
        int d = d0 + td + 16 * j;
        double inv = (double)bnw[d] / sqrt((double)bnv[d] + 1e-5);
        double sh  = (double)bnb[d] - (double)bnm[d] * inv;
        double bs  = (double)bias[d];
        #pragma unroll
        for (int i = 0; i < 4; ++i) {
            int m = m0 + tm + 16 * i;
            out[(size_t)m * 512 + d] = (float)((acc[i][j] + bs) * inv + sh);
        }
    }
}

// ---------------------------------------------------------------------------
// LIF (v_th=1.0) over T=4 on Y (T,B,N,C) fp32; pack spikes into per-(t,b,h,n)
// 64-bit masks (bit e = spike of channel h*64+e) via wave ballot.
__global__ void lif_mask(const float* __restrict__ Y, u64* __restrict__ msk) {
    int g = blockIdx.x * TPB + threadIdx.x;      // (b,n,c), 2M threads
    int c = g & 511, n = (g >> 9) & 511, b = g >> 18;
    int h = c >> 6;
    int lane = threadIdx.x & 63;
    double v = 0.0;
    for (int t = 0; t < 4; ++t) {
        float y = Y[((size_t)((t * 8 + b) * 512 + n) << 9) + c];
        double hh = v + ((double)y - v) * 0.5;
        bool s = hh >= 1.0;
        u64 mk = __ballot(s);
        if (lane == 0) msk[((t * 8 + b) * 8 + h) * 512 + n] = mk;
        v = s ? 0.0 : hh;
    }
}

// ---------------------------------------------------------------------------
// Retention core, fused with retention LIF (v_th=0.5).
// Per wave: one (b,h,n); lane = head-dim d. For each t:
//   acc[d] = sum_m popc(q_n & k_m) * gamma^|n-m| * v_bit(m,d)   (fp64)
//   x = 0.125*acc ; LIF(0.5) over t ; write spike r[t,b,n,h*64+d] (fp32)
__global__ __launch_bounds__(256) void retention(
    const u64* __restrict__ qm, const u64* __restrict__ km,
    const u64* __restrict__ vm, const double* __restrict__ pw,
    float* __restrict__ r)
{
    int bid = blockIdx.x;                 // 8192 = b(8) * h(8) * ng(128)
    int ng = bid & 127;
    int h  = (bid >> 7) & 7;
    int b  = bid >> 10;
    int wid  = threadIdx.x >> 6;
    int lane = threadIdx.x & 63;
    int n = ng * 4 + wid;

    __shared__ u64 km_s[512];
    __shared__ u64 vm_s[512];
    __shared__ double pw_s[512];

    for (int i = threadIdx.x; i < 512; i += 256) pw_s[i] = pw[h * 512 + i];

    double vstate = 0.0;
    for (int t = 0; t < 4; ++t) {
        int base = ((t * 8 + b) * 8 + h) * 512;
        __syncthreads();
        for (int i = threadIdx.x; i < 512; i += 256) {
            km_s[i] = km[base + i];
            vm_s[i] = vm[base + i];
        }
        __syncthreads();
        u64 qn = qm[base + n];
        double acc = 0.0;
        #pragma unroll 4
        for (int m = 0; m < 512; ++m) {
            int cnt = __popcll(qn & km_s[m]);
            int dist = n - m; dist = dist < 0 ? -dist : dist;
            double w = (double)cnt * pw_s[dist];
            acc += ((vm_s[m] >> lane) & 1ULL) ? w : 0.0;
        }
        double x = acc * 0.125;
        double hh = vstate + (x - vstate) * 0.5;
        bool s = hh >= 0.5;
        r[((size_t)((t * 8 + b) * 512 + n) << 9) + h * 64 + lane] = s ? 1.0f : 0.0f;
        vstate = s ? 0.0 : hh;
    }
}

// ---------------------------------------------------------------------------
// Final LIF (v_th=1.0) over T on Y (T,B,N,C); writes {0,1} fp32 to out.
__global__ void final_lif(const float* __restrict__ Y, float* __restrict__ out) {
    int g = blockIdx.x * TPB + threadIdx.x;
    int c = g & 511, n = (g >> 9) & 511, b = g >> 18;
    double v = 0.0;
    for (int t = 0; t < 4; ++t) {
        size_t idx = ((size_t)((t * 8 + b) * 512 + n) << 9) + c;
        float y = Y[idx];
        double hh = v + ((double)y - v) * 0.5;
        bool s = hh >= 1.0;
        out[idx] = s ? 1.0f : 0.0f;
        v = s ? 0.0 : hh;
    }
}

// ---------------------------------------------------------------------------
extern "C" void kernel_launch(void* const* d_in, const int* in_sizes, int n_in,
                              void* d_out, int out_size, void* d_ws, size_t ws_size,
                              hipStream_t stream) {
    const float* x = (const float*)d_in[0];
    const float *w[4], *bi[4], *bnw[4], *bnb[4], *bnm[4], *bnv[4];
    for (int br = 0; br < 4; ++br) {
        int base = 1 + br * 6;
        w[br]   = (const float*)d_in[base + 0];
        bi[br]  = (const float*)d_in[base + 1];
        bnw[br] = (const float*)d_in[base + 2];
        bnb[br] = (const float*)d_in[base + 3];
        bnm[br] = (const float*)d_in[base + 4];
        bnv[br] = (const float*)d_in[base + 5];
    }

    char* p = (char*)d_ws;
    double* pw = (double*)p;  p += 8 * 512 * sizeof(double);      // 32 KB
    u64* qm = (u64*)p;        p += 131072 * sizeof(u64);          // 1 MB
    u64* km = (u64*)p;        p += 131072 * sizeof(u64);          // 1 MB
    u64* vm = (u64*)p;        p += 131072 * sizeof(u64);          // 1 MB
    float* Y = (float*)p;     p += (size_t)16384 * 512 * 4;       // 33.5 MB
    float* r = (float*)d_out;  // retention spikes staged in d_out, consumed
                               // by the p-GEMM, then d_out is fully rewritten.

    pow_kernel<<<1, 64, 0, stream>>>(pw);

    dim3 gg(256, 8);
    // q branch
    gemm_bn<<<gg, 256, 0, stream>>>(x, w[0], bi[0], bnw[0], bnb[0], bnm[0], bnv[0], Y);
    lif_mask<<<8192, TPB, 0, stream>>>(Y, qm);
    // k branch
    gemm_bn<<<gg, 256, 0, stream>>>(x, w[1], bi[1], bnw[1], bnb[1], bnm[1], bnv[1], Y);
    lif_mask<<<8192, TPB, 0, stream>>>(Y, km);
    // v branch
    gemm_bn<<<gg, 256, 0, stream>>>(x, w[2], bi[2], bnw[2], bnb[2], bnm[2], bnv[2], Y);
    lif_mask<<<8192, TPB, 0, stream>>>(Y, vm);

    // retention + retention LIF -> spikes r (staged in d_out)
    retention<<<8192, TPB, 0, stream>>>(qm, km, vm, pw, r);

    // output projection + BN (fp64 acc), then final LIF -> d_out
    gemm_bn<<<gg, 256, 0, stream>>>(r, w[3], bi[3], bnw[3], bnb[3], bnm[3], bnv[3], Y);
    final_lif<<<8192, TPB, 0, stream>>>(Y, (float*)d_out);
}

// Round 2
// 1416.655 us; speedup vs baseline: 1.8794x; 1.8794x over previous
//
#include <hip/hip_runtime.h>
#include <cstdint>

typedef unsigned long long u64;

#define TPB 256

static __device__ __forceinline__ u64 rfl64(u64 x) {
    unsigned lo = __builtin_amdgcn_readfirstlane((unsigned)x);
    unsigned hi = __builtin_amdgcn_readfirstlane((unsigned)(x >> 32));
    return ((u64)hi << 32) | (u64)lo;
}

// ---------------------------------------------------------------------------
// gamma^dist table, fp64. pw[h*512 + dist]
__global__ void pow_kernel(double* __restrict__ pw) {
    int h = threadIdx.x;
    if (h < 8) {
        double gamma = 1.0 - ldexp(1.0, -5 - h);   // 1 - 2^-(5+h), exact
        double p = 1.0;
        for (int i = 0; i < 512; ++i) { pw[h * 512 + i] = p; p *= gamma; }
    }
}

// ---------------------------------------------------------------------------
// out[m,d] = BN( sum_c A[m,c]*W[d,c] + bias[d] ), fp64 accumulation.
__global__ __launch_bounds__(256) void gemm_bn(
    const float* __restrict__ A, const float* __restrict__ W,
    const float* __restrict__ bias,
    const float* __restrict__ bnw, const float* __restrict__ bnb,
    const float* __restrict__ bnm, const float* __restrict__ bnv,
    float* __restrict__ out)
{
    const int K = 512;
    __shared__ float As[64][36];
    __shared__ float Ws[64][36];

    const int tid = threadIdx.x;
    const int m0 = blockIdx.x * 64;
    const int d0 = blockIdx.y * 64;
    const int lr = tid >> 3;
    const int lc = (tid & 7) << 2;
    const int tm = tid >> 4;
    const int td = tid & 15;

    double acc[4][4];
    #pragma unroll
    for (int i = 0; i < 4; ++i)
        #pragma unroll
        for (int j = 0; j < 4; ++j) acc[i][j] = 0.0;

    for (int k0 = 0; k0 < K; k0 += 32) {
        float4 a0 = *(const float4*)(A + (size_t)(m0 + lr) * K + k0 + lc);
        float4 a1 = *(const float4*)(A + (size_t)(m0 + lr + 32) * K + k0 + lc);
        float4 w0 = *(const float4*)(W + (size_t)(d0 + lr) * K + k0 + lc);
        float4 w1 = *(const float4*)(W + (size_t)(d0 + lr + 32) * K + k0 + lc);
        __syncthreads();
        *(float4*)&As[lr][lc]      = a0;
        *(float4*)&As[lr + 32][lc] = a1;
        *(float4*)&Ws[lr][lc]      = w0;
        *(float4*)&Ws[lr + 32][lc] = w1;
        __syncthreads();
        #pragma unroll 8
        for (int kk = 0; kk < 32; ++kk) {
            double av[4], wv[4];
            #pragma unroll
            for (int i = 0; i < 4; ++i) av[i] = (double)As[tm + 16 * i][kk];
            #pragma unroll
            for (int j = 0; j < 4; ++j) wv[j] = (double)Ws[td + 16 * j][kk];
            #pragma unroll
            for (int i = 0; i < 4; ++i)
                #pragma unroll
                for (int j = 0; j < 4; ++j)
                    acc[i][j] += av[i] * wv[j];
        }
    }

    #pragma unroll
    for (int j = 0; j < 4; ++j) {
        int d = d0 + td + 16 * j;
        double inv = (double)bnw[d] / sqrt((double)bnv[d] + 1e-5);
        double sh  = (double)bnb[d] - (double)bnm[d] * inv;
        double bs  = (double)bias[d];
        #pragma unroll
        for (int i = 0; i < 4; ++i) {
            int m = m0 + tm + 16 * i;
            out[(size_t)m * 512 + d] = (float)((acc[i][j] + bs) * inv + sh);
        }
    }
}

// ---------------------------------------------------------------------------
// LIF (v_th=1.0) over T=4 on Y; pack spikes into per-(t,b,h,n) 64-bit masks.
__global__ void lif_mask(const float* __restrict__ Y, u64* __restrict__ msk) {
    int g = blockIdx.x * TPB + threadIdx.x;
    int c = g & 511, n = (g >> 9) & 511, b = g >> 18;
    int h = c >> 6;
    int lane = threadIdx.x & 63;
    double v = 0.0;
    for (int t = 0; t < 4; ++t) {
        float y = Y[((size_t)((t * 8 + b) * 512 + n) << 9) + c];
        double hh = v + ((double)y - v) * 0.5;
        bool s = hh >= 1.0;
        u64 mk = __ballot(s);
        if (lane == 0) msk[((t * 8 + b) * 8 + h) * 512 + n] = mk;
        v = s ? 0.0 : hh;
    }
}

// ---------------------------------------------------------------------------
// Retention + retention LIF, restructured: lane = n (64 rows/wave),
// d = 64 fp64 register accumulators; k/v masks read as wave-uniform scalars.
// Block = 4 waves = the 4 time steps of one (b,h,ngroup); LIF vstate is
// chained wave->wave through LDS (XOR-swizzled) with barriers.
__global__ __launch_bounds__(256) void retention2(
    const u64* __restrict__ qm, const u64* __restrict__ km,
    const u64* __restrict__ vm, const double* __restrict__ pw,
    float* __restrict__ r)
{
    int bid = blockIdx.x;            // 512 = b(8) * h(8) * ng(8)
    int ng = bid & 7;
    int h  = (bid >> 3) & 7;
    int b  = bid >> 6;
    int t    = threadIdx.x >> 6;     // wave id == time step
    int lane = threadIdx.x & 63;
    int n = ng * 64 + lane;

    __shared__ double pw_s[512];
    __shared__ double vs_s[64 * 64];  // vstate hand-off between t-waves

    for (int i = threadIdx.x; i < 512; i += 256) pw_s[i] = pw[h * 512 + i];
    __syncthreads();

    int base = ((t * 8 + b) * 8 + h) * 512;
    u64 qn = qm[base + n];

    double acc[64];
    #pragma unroll
    for (int d = 0; d < 64; ++d) acc[d] = 0.0;

    const u64* kp = km + base;
    const u64* vp = vm + base;
    for (int m = 0; m < 512; ++m) {
        u64 kv = rfl64(kp[m]);       // wave-uniform -> SGPR
        u64 vv = rfl64(vp[m]);
        int dist = n - m; if (dist < 0) dist = -dist;
        double w = (double)__popcll(qn & kv) * pw_s[dist];
        #pragma unroll
        for (int d = 0; d < 64; ++d)
            acc[d] = fma(w, ((vv >> d) & 1ULL) ? 1.0 : 0.0, acc[d]);
    }

    __syncthreads();
    // LIF chain across the 4 t-waves, v_th = 0.5, hard reset
    for (int tt = 0; tt < 4; ++tt) {
        if (tt == t) {
            size_t rbase = ((size_t)((t * 8 + b) * 512 + n) << 9) + h * 64;
            #pragma unroll
            for (int d = 0; d < 64; ++d) {
                double v = (t == 0) ? 0.0 : vs_s[lane * 64 + (d ^ lane)];
                double x = acc[d] * 0.125;
                double hh = v + (x - v) * 0.5;
                bool s = hh >= 0.5;
                r[rbase + d] = s ? 1.0f : 0.0f;
                if (t < 3) vs_s[lane * 64 + (d ^ lane)] = s ? 0.0 : hh;
            }
        }
        __syncthreads();
    }
}

// ---------------------------------------------------------------------------
// Final LIF (v_th=1.0) over T on Y; writes {0,1} fp32 to out.
__global__ void final_lif(const float* __restrict__ Y, float* __restrict__ out) {
    int g = blockIdx.x * TPB + threadIdx.x;
    int c = g & 511, n = (g >> 9) & 511, b = g >> 18;
    double v = 0.0;
    for (int t = 0; t < 4; ++t) {
        size_t idx = ((size_t)((t * 8 + b) * 512 + n) << 9) + c;
        float y = Y[idx];
        double hh = v + ((double)y - v) * 0.5;
        bool s = hh >= 1.0;
        out[idx] = s ? 1.0f : 0.0f;
        v = s ? 0.0 : hh;
    }
}

// ---------------------------------------------------------------------------
extern "C" void kernel_launch(void* const* d_in, const int* in_sizes, int n_in,
                              void* d_out, int out_size, void* d_ws, size_t ws_size,
                              hipStream_t stream) {
    const float* x = (const float*)d_in[0];
    const float *w[4], *bi[4], *bnw[4], *bnb[4], *bnm[4], *bnv[4];
    for (int br = 0; br < 4; ++br) {
        int base = 1 + br * 6;
        w[br]   = (const float*)d_in[base + 0];
        bi[br]  = (const float*)d_in[base + 1];
        bnw[br] = (const float*)d_in[base + 2];
        bnb[br] = (const float*)d_in[base + 3];
        bnm[br] = (const float*)d_in[base + 4];
        bnv[br] = (const float*)d_in[base + 5];
    }

    char* p = (char*)d_ws;
    double* pw = (double*)p;  p += 8 * 512 * sizeof(double);      // 32 KB
    u64* qm = (u64*)p;        p += 131072 * sizeof(u64);          // 1 MB
    u64* km = (u64*)p;        p += 131072 * sizeof(u64);          // 1 MB
    u64* vm = (u64*)p;        p += 131072 * sizeof(u64);          // 1 MB
    float* Y = (float*)p;     p += (size_t)16384 * 512 * 4;       // 33.5 MB
    float* r = (float*)d_out;  // retention spikes staged in d_out, consumed
                               // by the p-GEMM, then d_out fully rewritten.

    pow_kernel<<<1, 64, 0, stream>>>(pw);

    dim3 gg(256, 8);
    gemm_bn<<<gg, 256, 0, stream>>>(x, w[0], bi[0], bnw[0], bnb[0], bnm[0], bnv[0], Y);
    lif_mask<<<8192, TPB, 0, stream>>>(Y, qm);
    gemm_bn<<<gg, 256, 0, stream>>>(x, w[1], bi[1], bnw[1], bnb[1], bnm[1], bnv[1], Y);
    lif_mask<<<8192, TPB, 0, stream>>>(Y, km);
    gemm_bn<<<gg, 256, 0, stream>>>(x, w[2], bi[2], bnw[2], bnb[2], bnm[2], bnv[2], Y);
    lif_mask<<<8192, TPB, 0, stream>>>(Y, vm);

    retention2<<<512, TPB, 0, stream>>>(qm, km, vm, pw, r);

    gemm_bn<<<gg, 256, 0, stream>>>(r, w[3], bi[3], bnw[3], bnb[3], bnm[3], bnv[3], Y);
    final_lif<<<8192, TPB, 0, stream>>>(Y, (float*)d_out);
}